// Round 6
// baseline (3422.195 us; speedup 1.0000x reference)
//
#include <hip/hip_runtime.h>
#include <stdint.h>

namespace {

constexpr int B_ROWS = 131072;

typedef __attribute__((ext_vector_type(8))) short bf16x8;
typedef __attribute__((ext_vector_type(4))) float f32x4;

__device__ __forceinline__ unsigned short f2bf(float f) {
  unsigned u = __builtin_bit_cast(unsigned, f);
  u += 0x7fffu + ((u >> 16) & 1u);
  return (unsigned short)(u >> 16);
}
__device__ __forceinline__ float bf2f(unsigned short h) {
  unsigned u = ((unsigned)h) << 16;
  return __builtin_bit_cast(float, u);
}
__device__ __forceinline__ float sigm(float v) { return 1.0f / (1.0f + __expf(-v)); }

// ---------- weight packing ----------

__global__ void pack_t_k(const float* __restrict__ W, unsigned short* __restrict__ Wt) {
  int idx = blockIdx.x * 256 + threadIdx.x;  // 512*512
  int n = idx >> 9, k = idx & 511;
  Wt[idx] = f2bf(W[(k << 9) + n]);
}

__global__ void pack_zgr_k(const float* __restrict__ dgmW, unsigned short* __restrict__ Wt) {
  long idx = (long)blockIdx.x * 256 + threadIdx.x;  // 3*1536*1024
  int l = (int)(idx / (1536 * 1024));
  int rest = (int)(idx - (long)l * (1536 * 1024));
  int n = rest >> 10, k = rest & 1023;
  int g = n >> 9, nn = n & 511;
  const int xi0[3] = {0, 3, 6};
  const int xi1[3] = {2, 4, 8};
  const int si[3] = {1, 5, 7};
  float v;
  if (k < 512)
    v = dgmW[(((long)(l * 12 + xi0[g]) << 9) + k) * 512 + nn] +
        dgmW[(((long)(l * 12 + xi1[g]) << 9) + k) * 512 + nn];
  else
    v = dgmW[(((long)(l * 12 + si[g]) << 9) + (k - 512)) * 512 + nn];
  Wt[idx] = f2bf(v);
}

__global__ void pack_h_k(const float* __restrict__ dgmW, unsigned short* __restrict__ Wt) {
  long idx = (long)blockIdx.x * 256 + threadIdx.x;  // 3*512*1024
  int l = (int)(idx / (512 * 1024));
  int rest = (int)(idx - (long)l * (512 * 1024));
  int n = rest >> 10, k = rest & 1023;
  float v;
  if (k < 512)
    v = dgmW[(((long)(l * 12 + 9) << 9) + k) * 512 + n] +
        dgmW[(((long)(l * 12 + 11) << 9) + k) * 512 + n];
  else
    v = dgmW[(((long)(l * 12 + 10) << 9) + (k - 512)) * 512 + n];
  Wt[idx] = f2bf(v);
}

__global__ void pack_bias_k(const float* __restrict__ dgmb, float* __restrict__ bzgr,
                            float* __restrict__ bh) {
  int idx = blockIdx.x * 256 + threadIdx.x;  // 3*2048
  if (idx >= 3 * 2048) return;
  int l = idx >> 11, n = idx & 2047;
  const float* bl = dgmb + l * 12 * 512;
  if (n < 1536) {
    int g = n >> 9, nn = n & 511;
    bzgr[l * 1536 + n] =
        bl[(g * 3 + 0) * 512 + nn] + bl[(g * 3 + 1) * 512 + nn] + bl[(g * 3 + 2) * 512 + nn];
  } else {
    int nn = n - 1536;
    bh[l * 512 + nn] = bl[9 * 512 + nn] + bl[10 * 512 + nn] + bl[11 * 512 + nn];
  }
}

// ---------- front input layer ----------
__global__ void front0_k(const float* __restrict__ X, const float* __restrict__ t,
                         const float* __restrict__ Win, const float* __restrict__ bin,
                         unsigned short* __restrict__ x0, long row0) {
  long idx = (long)blockIdx.x * 256 + threadIdx.x;  // rows*512
  long r = idx >> 9;
  int c = (int)(idx & 511);
  long gr = row0 + r;
  float a = X[gr * 2] * Win[c] + X[gr * 2 + 1] * Win[512 + c] + t[gr] * Win[1024 + c] + bin[c];
  x0[idx] = f2bf(tanhf(a));
}

// ---------- output head ----------
__global__ void head_k(const unsigned short* __restrict__ S, const float* __restrict__ Wout,
                       const float* __restrict__ bout, float* __restrict__ out, long row0) {
  const int lane = threadIdx.x & 63, wid = threadIdx.x >> 6;
  const long r = (long)blockIdx.x * 4 + wid;
  bf16x8 sv = *(const bf16x8*)&S[r * 512 + lane * 8];
  float sum = 0.f;
#pragma unroll
  for (int i = 0; i < 8; ++i) sum += bf2f((unsigned short)sv[i]) * Wout[lane * 8 + i];
#pragma unroll
  for (int off = 32; off > 0; off >>= 1) sum += __shfl_down(sum, off);
  if (lane == 0) out[row0 + r] = sum + bout[0];
}

// ---------- persistent-M 256x256 8-phase GEMM, READ-AHEAD pipelined ----------
// R5 post-mortem fix: each phase issues the NEXT phase's ds_reads into the
// alternate register-fragment set BEFORE the current MFMA cluster, so the
// LDS pipe runs concurrently with the MFMA pipe (counted lgkm waits emitted
// by the compiler from data deps). Staging safety: every region staged in
// phase p had its last ds_read issued <= p-2 and consumed before the end-bar
// of p-1 (derivation in R5 notes). vmcnt(8) sits BEFORE the P2/P4 reads
// (exactly 8 loads are younger than the unit those reads consume).
template <int EPI, int KT, int LOGKT, int NCOL>
__global__ __launch_bounds__(512, 2) void gemmP_k(
    const unsigned short* __restrict__ a0, const unsigned short* __restrict__ a1,
    const unsigned short* __restrict__ wt, const float* __restrict__ bias,
    unsigned short* __restrict__ o0, unsigned short* __restrict__ o1,
    unsigned short* __restrict__ o2, const unsigned short* __restrict__ e0,
    const unsigned short* __restrict__ e1, int njobs, int jpb) {
  constexpr int K = KT * 64;
  extern __shared__ unsigned short lds[];
  const int tid = threadIdx.x;
  const int lane = tid & 63, wid = tid >> 6;
  const int wm = wid >> 2, wn = wid & 3;
  const int lr = lane & 15, kk = lane >> 4;

  // XCD-contiguous bijective block swizzle (m204) on [0,G)
  const int G = gridDim.x;
  const int q = G >> 3, rr = G & 7;
  const int xcd = (int)blockIdx.x & 7, lo = (int)blockIdx.x >> 3;
  const int bsw = ((xcd < rr) ? xcd * (q + 1) : rr * (q + 1) + (xcd - rr) * q) + lo;
  const int j0 = bsw * jpb;
  if (j0 >= njobs) return;
  const int nj = min(jpb, njobs - j0);
  const int nseq = nj << LOGKT;

  // lane-constant address pieces (swizzle granule gp = kk ^ ((lr>>1)&3))
  const int gp8 = ((kk ^ ((lr >> 1) & 3)) << 3);
  const int a_rd = (wm * 128 + lr) * 32 + gp8;         // + mh*2048 + m*512 + ks*8192 + cbo
  const int b_rd = 16384 + (wn * 64 + lr) * 32 + gp8;  // + n*512 + ks*8192 + cbo
  // stage lane pieces
  const int r0 = tid >> 2, gl0 = (tid & 3) ^ ((r0 >> 1) & 3);
  const int c1 = tid + 512, r1 = c1 >> 2, gl1 = (c1 & 3) ^ ((r1 >> 1) & 3);
  const int aL0 = r0 * 512 + gl0 * 8, aL1 = r1 * 512 + gl1 * 8;
  const size_t bL0 = (size_t)r0 * K + gl0 * 8, bL1 = (size_t)r1 * K + gl1 * 8;
  const int dL0 = tid * 8, dL1 = (tid + 512) * 8;

  f32x4 acc[8][4] = {};
  bf16x8 afA[4], afB[4], bfA[4], bfB[4];

  auto stA = [&](int s2, int ks) {
    if (s2 >= nseq) return;
    const int jj = j0 + (s2 >> LOGKT);
    const int mt = jj / NCOL;
    const int kt2 = s2 & (KT - 1);
    const unsigned short* src = (KT == 16 && (kt2 & 8)) ? a1 : a0;
    const long pb = (long)mt * 131072 + (kt2 & 7) * 64 + ks * 32;
    const int d = ((s2 & 1) << 15) + ks * 8192;
    __builtin_amdgcn_global_load_lds(
        (const __attribute__((address_space(1))) void*)(src + pb + aL0),
        (__attribute__((address_space(3))) void*)(lds + d + dL0), 16, 0, 0);
    __builtin_amdgcn_global_load_lds(
        (const __attribute__((address_space(1))) void*)(src + pb + aL1),
        (__attribute__((address_space(3))) void*)(lds + d + dL1), 16, 0, 0);
  };
  auto stB = [&](int s2, int ks) {
    if (s2 >= nseq) return;
    const int jj = j0 + (s2 >> LOGKT);
    const int col = jj % NCOL;
    const int kt2 = s2 & (KT - 1);
    const size_t pb = (size_t)col * (256 * K) + kt2 * 64 + ks * 32;
    const int d = ((s2 & 1) << 15) + 16384 + ks * 8192;
    __builtin_amdgcn_global_load_lds(
        (const __attribute__((address_space(1))) void*)(wt + pb + bL0),
        (__attribute__((address_space(3))) void*)(lds + d + dL0), 16, 0, 0);
    __builtin_amdgcn_global_load_lds(
        (const __attribute__((address_space(1))) void*)(wt + pb + bL1),
        (__attribute__((address_space(3))) void*)(lds + d + dL1), 16, 0, 0);
  };

#define LDA(dst, cbo_, mh, ks_)                                                           \
  _Pragma("unroll") for (int _m = 0; _m < 4; ++_m) dst[_m] =                              \
      *(const bf16x8*)(lds + (cbo_) + (ks_)*8192 + a_rd + (mh)*2048 + _m * 512);

#define LDB(dst, cbo_, ks_)                                                               \
  _Pragma("unroll") for (int _n = 0; _n < 4; ++_n) dst[_n] =                              \
      *(const bf16x8*)(lds + (cbo_) + (ks_)*8192 + b_rd + _n * 512);

#define MMQ(mh, AF, BF)                                                                   \
  do {                                                                                    \
    __builtin_amdgcn_s_setprio(1);                                                        \
    _Pragma("unroll") for (int _m = 0; _m < 4; ++_m) _Pragma("unroll") for (int _n = 0;   \
                                                                            _n < 4; ++_n) \
        acc[(mh)*4 + _m][_n] = __builtin_amdgcn_mfma_f32_16x16x32_bf16(                   \
            AF[_m], BF[_n], acc[(mh)*4 + _m][_n], 0, 0, 0);                               \
    __builtin_amdgcn_s_setprio(0);                                                        \
  } while (0)

  // prologue: stage tile0 {Bks0,Aks0,Bks1,Aks1} + tile1 {Bks0,Aks0,Bks1}
  stB(0, 0);
  stA(0, 0);
  stB(0, 1);
  stA(0, 1);
  stB(1, 0);
  stA(1, 0);
  stB(1, 1);
  asm volatile("s_waitcnt vmcnt(10)" ::: "memory");  // tile0 ks0 landed (10 younger)
  __builtin_amdgcn_s_barrier();
  LDB(bfA, 0, 0);
  LDA(afA, 0, 0, 0);

  for (int s = 0; s < nseq; ++s) {
    const int cbo = (s & 1) << 15;
    const int cbn = cbo ^ 32768;
    const bool deep = (s + 4 <= nseq);
    // P1: MFMA rows0-3 (afA x bfA, ks0); read afB = A(m4-7,ks0); stage A(s+1,ks1)
    LDA(afB, cbo, 1, 0);
    stA(s + 1, 1);
    __builtin_amdgcn_s_barrier();
    MMQ(0, afA, bfA);
    __builtin_amdgcn_s_barrier();
    // P2: read ks1 frags (tile s); stage B(s+2,ks0); MFMA rows4-7 (afB x bfA)
    if (deep)
      asm volatile("s_waitcnt vmcnt(8)" ::: "memory");
    else
      asm volatile("s_waitcnt vmcnt(0)" ::: "memory");
    LDB(bfB, cbo, 1);
    LDA(afA, cbo, 0, 1);
    stB(s + 2, 0);
    __builtin_amdgcn_s_barrier();
    MMQ(1, afB, bfA);
    __builtin_amdgcn_s_barrier();
    // P3: read afB = A(m4-7,ks1); stage A(s+2,ks0); MFMA rows0-3 (afA x bfB)
    LDA(afB, cbo, 1, 1);
    stA(s + 2, 0);
    __builtin_amdgcn_s_barrier();
    MMQ(0, afA, bfB);
    __builtin_amdgcn_s_barrier();
    // P4: read NEXT tile ks0 frags (parity cbn); stage B(s+2,ks1); MFMA rows4-7 (afB x bfB)
    if (deep)
      asm volatile("s_waitcnt vmcnt(8)" ::: "memory");
    else
      asm volatile("s_waitcnt vmcnt(0)" ::: "memory");
    LDB(bfA, cbn, 0);
    LDA(afA, cbn, 0, 0);
    stB(s + 2, 1);
    __builtin_amdgcn_s_barrier();
    MMQ(1, afB, bfB);
    __builtin_amdgcn_s_barrier();

    if ((s & (KT - 1)) == (KT - 1)) {
      // epilogue for finished job
      const int jj = j0 + (s >> LOGKT);
      const long brow = (long)(jj / NCOL) * 256;
      const int bcol = (jj % NCOL) * 256;
#pragma unroll
      for (int m = 0; m < 8; ++m) {
#pragma unroll
        for (int n = 0; n < 4; ++n) {
          const int col = bcol + wn * 64 + n * 16 + lr;
          const float bs = bias[col];
#pragma unroll
          for (int j = 0; j < 4; ++j) {
            const long row = brow + wm * 128 + m * 16 + kk * 4 + j;
            float v = acc[m][n][j] + bs;
            if constexpr (EPI == 0) {
              o0[row * 512 + col] = f2bf(tanhf(v));
            } else if constexpr (EPI == 1) {
              unsigned short b = f2bf(v);
              o0[row * 512 + col] = b;
              o1[row * 512 + col] = b;
            } else if constexpr (EPI == 2) {
              const int g = col >> 9;
              const int nn = col & 511;
              const float sgv = sigm(v);
              if (g == 0) {
                o0[row * 512 + nn] = f2bf(sgv * bf2f(e0[row * 512 + nn]));  // Z*S
              } else if (g == 1) {
                o1[row * 512 + nn] = f2bf(1.0f - sgv);  // 1-G
              } else {
                o2[row * 512 + nn] = f2bf(sgv * bf2f(e0[row * 512 + nn]));  // S*R
              }
            } else {
              const float h = tanhf(v);
              const float omg = bf2f(e0[row * 512 + col]);
              const float zs = bf2f(e1[row * 512 + col]);
              o0[row * 512 + col] = f2bf(omg * h + zs);  // S_new
            }
            acc[m][n][j] = 0.0f;
          }
        }
      }
    }
  }
#undef LDA
#undef LDB
#undef MMQ
}

}  // namespace

extern "C" void kernel_launch(void* const* d_in, const int* in_sizes, int n_in,
                              void* d_out, int out_size, void* d_ws, size_t ws_size,
                              hipStream_t stream) {
  const float* X = (const float*)d_in[0];
  const float* t = (const float*)d_in[1];
  const float* W_in = (const float*)d_in[2];
  const float* b_in = (const float*)d_in[3];
  const float* W_h1 = (const float*)d_in[4];
  const float* b_h1 = (const float*)d_in[5];
  const float* W_hd = (const float*)d_in[6];
  const float* b_hd = (const float*)d_in[7];
  const float* dgm_W = (const float*)d_in[8];
  const float* dgm_b = (const float*)d_in[9];
  const float* W_out = (const float*)d_in[10];
  const float* b_out = (const float*)d_in[11];
  float* out = (float*)d_out;
  char* ws = (char*)d_ws;

  // allow 128 KiB dynamic LDS (host-side, capture-safe)
  (void)hipFuncSetAttribute((const void*)&gemmP_k<0, 8, 3, 2>,
                            hipFuncAttributeMaxDynamicSharedMemorySize, 131072);
  (void)hipFuncSetAttribute((const void*)&gemmP_k<1, 8, 3, 2>,
                            hipFuncAttributeMaxDynamicSharedMemorySize, 131072);
  (void)hipFuncSetAttribute((const void*)&gemmP_k<2, 16, 4, 6>,
                            hipFuncAttributeMaxDynamicSharedMemorySize, 131072);
  (void)hipFuncSetAttribute((const void*)&gemmP_k<3, 16, 4, 2>,
                            hipFuncAttributeMaxDynamicSharedMemorySize, 131072);

  size_t off = 0;
  auto alloc = [&](size_t bytes) {
    size_t o = off;
    off = (off + bytes + 255) & ~(size_t)255;
    return o;
  };
  size_t o_wth1 = alloc((size_t)512 * 512 * 2);
  size_t o_wthd = alloc((size_t)512 * 512 * 2);
  size_t o_wtzgr = alloc((size_t)3 * 1536 * 1024 * 2);
  size_t o_wth = alloc((size_t)3 * 512 * 1024 * 2);
  size_t o_bzgr = alloc((size_t)3 * 1536 * 4);
  size_t o_bh = alloc((size_t)3 * 512 * 4);
  size_t actoff = off;

  unsigned short* wth1 = (unsigned short*)(ws + o_wth1);
  unsigned short* wthd = (unsigned short*)(ws + o_wthd);
  unsigned short* wtzgr = (unsigned short*)(ws + o_wtzgr);
  unsigned short* wth = (unsigned short*)(ws + o_wth);
  float* bzgr = (float*)(ws + o_bzgr);
  float* bh = (float*)(ws + o_bh);

  // chunk batch: 5 bf16 [R,512] activation buffers in remaining ws; R % 256 == 0
  size_t avail = ws_size > actoff ? ws_size - actoff : 0;
  int nch = 1;
  while (nch < 256 && (size_t)(B_ROWS / nch) * 512 * 2 * 5 > avail) nch <<= 1;
  const int R = B_ROWS / nch;
  unsigned short* xb = (unsigned short*)(ws + actoff);
  unsigned short* Sb = xb + (size_t)R * 512;
  unsigned short* ZSb = Sb + (size_t)R * 512;
  unsigned short* OGb = ZSb + (size_t)R * 512;
  unsigned short* SRb = OGb + (size_t)R * 512;

  pack_t_k<<<1024, 256, 0, stream>>>(W_h1, wth1);
  pack_t_k<<<1024, 256, 0, stream>>>(W_hd, wthd);
  pack_zgr_k<<<18432, 256, 0, stream>>>(dgm_W, wtzgr);
  pack_h_k<<<6144, 256, 0, stream>>>(dgm_W, wth);
  pack_bias_k<<<24, 256, 0, stream>>>(dgm_b, bzgr, bh);

  const int MT = R / 256;
  auto cfg = [](int njobs, int& jpb, int& G) {
    jpb = (njobs + 255) / 256;
    G = (njobs + jpb - 1) / jpb;
  };
  int nj2 = 2 * MT, jpb2, G2;
  cfg(nj2, jpb2, G2);
  int nj6 = 6 * MT, jpb6, G6;
  cfg(nj6, jpb6, G6);

  for (int c = 0; c < nch; ++c) {
    long row0 = (long)c * R;
    // x0 = tanh(inp@W_in + b_in)  -> ZSb (scratch)
    front0_k<<<R * 2, 256, 0, stream>>>(X, t, W_in, b_in, ZSb, row0);
    // x1 = tanh(x0@W_h1 + b_h1)   -> OGb (scratch)
    gemmP_k<0, 8, 3, 2><<<G2, 512, 131072, stream>>>(ZSb, ZSb, wth1, b_h1, OGb, nullptr,
                                                     nullptr, nullptr, nullptr, nj2, jpb2);
    // x = x1@W_hd + b_hd          -> xb and Sb
    gemmP_k<1, 8, 3, 2><<<G2, 512, 131072, stream>>>(OGb, OGb, wthd, b_hd, xb, Sb, nullptr,
                                                     nullptr, nullptr, nj2, jpb2);
    for (int l = 0; l < 3; ++l) {
      // gates: [x|S] @ Wzgr -> Z*S, 1-G, S*R
      gemmP_k<2, 16, 4, 6><<<G6, 512, 131072, stream>>>(
          xb, Sb, wtzgr + (size_t)l * 1536 * 1024, bzgr + l * 1536, ZSb, OGb, SRb, Sb,
          nullptr, nj6, jpb6);
      // H + S update: [x|S*R] @ Wh ; S = (1-G)*tanh + Z*S
      gemmP_k<3, 16, 4, 2><<<G2, 512, 131072, stream>>>(
          xb, SRb, wth + (size_t)l * 512 * 1024, bh + l * 512, Sb, nullptr, nullptr, OGb,
          ZSb, nj2, jpb2);
    }
    head_k<<<R / 4, 256, 0, stream>>>(Sb, W_out, b_out, out, row0);
  }
}